// Round 2
// baseline (345.140 us; speedup 1.0000x reference)
//
#include <hip/hip_runtime.h>
#include <cstdint>
#include <cstddef>

typedef unsigned short u16;
typedef __attribute__((ext_vector_type(8))) short sh8;   // 8 bf16 (4 VGPR)
typedef __attribute__((ext_vector_type(4))) float f4;    // 4 f32

#define MFMA16(a, b, c) __builtin_amdgcn_mfma_f32_16x16x32_bf16((a), (b), (c), 0, 0, 0)

__device__ __forceinline__ u16 f2bf(float f) {
  union { float f; uint32_t u; } v; v.f = f;
  uint32_t u = v.u;
  uint32_t lsb = (u >> 16) & 1u;
  return (u16)((u + 0x7fffu + lsb) >> 16);   // RNE
}
__device__ __forceinline__ float bf2f(u16 h) {
  union { uint32_t u; float f; } v; v.u = ((uint32_t)h) << 16;
  return v.f;
}

// async global->LDS, 16B per lane. LDS dest must be linear in lane order.
__device__ __forceinline__ void aload16(const void* g, void* l) {
  __builtin_amdgcn_global_load_lds(
      (const __attribute__((address_space(1))) uint32_t*)g,
      (__attribute__((address_space(3))) uint32_t*)l, 16, 0, 0);
}

// ---------------------------------------------------------------------------
// Kernel 1: split fp32 weights into 3 bf16 planes (exact).
// ---------------------------------------------------------------------------
__global__ void prep_weights(const float* __restrict__ qw, const float* __restrict__ kw,
                             const float* __restrict__ vw, const float* __restrict__ pw,
                             u16* __restrict__ w3qkv, u16* __restrict__ w3p) {
  int row = blockIdx.x;  // 0..2047
  const float* src;
  u16* dst;
  int M, m;
  if (row < 1536) {
    int br = row >> 9;
    src = (br == 0 ? qw : (br == 1 ? kw : vw)) + (size_t)(row & 511) * 512;
    dst = w3qkv; M = 1536; m = row;
  } else {
    src = pw + (size_t)(row - 1536) * 512;
    dst = w3p; M = 512; m = row - 1536;
  }
  for (int c = threadIdx.x; c < 512; c += 256) {
    float w = src[c];
    u16 b0 = f2bf(w);  float h0 = bf2f(b0); float r1 = w - h0;
    u16 b1 = f2bf(r1); float h1 = bf2f(b1); float r2 = r1 - h1;
    u16 b2 = f2bf(r2);
    dst[(size_t)m * 512 + c] = b0;
    dst[(size_t)(M + m) * 512 + c] = b1;
    dst[(size_t)(2 * M + m) * 512 + c] = b2;
  }
}

__global__ void bn_prep(const float* __restrict__ g, const float* __restrict__ be,
                        const float* __restrict__ mu, const float* __restrict__ va,
                        float* __restrict__ inv, float* __restrict__ add) {
  #pragma clang fp contract(off)
  int i = blockIdx.x * 256 + threadIdx.x;
  if (i < 512) {
    float iv = g[i] / sqrtf(va[i] + 1e-5f);
    inv[i] = iv;
    add[i] = be[i] - mu[i] * iv;
  }
}

// ---------------------------------------------------------------------------
// Kernel 2: LIF over x -> spikes, stored TRANSPOSED sT[t][b][n][c] (bf16).
// ---------------------------------------------------------------------------
__global__ __launch_bounds__(256) void lif0(const float* __restrict__ x, u16* __restrict__ sT) {
  #pragma clang fp contract(off)
  __shared__ u16 st[64 * 80];   // [n][c] padded
  const int tid = threadIdx.x;
  const int n0 = blockIdx.x * 64;
  const int c0 = blockIdx.y * 64;
  const int b = blockIdx.z;
  const int cl = tid >> 2;
  const int ns = (tid & 3) * 16;
  const int nr = tid >> 2;
  const int cs = (tid & 3) * 16;
  float vv[16];
#pragma unroll
  for (int i = 0; i < 16; i++) vv[i] = 0.f;
  for (int t = 0; t < 4; ++t) {
    const float* xp = x + ((size_t)((t * 8 + b) * 512 + c0 + cl)) * 1024 + n0 + ns;
#pragma unroll
    for (int q = 0; q < 4; ++q) {
      f4 xv = *(const f4*)(xp + q * 4);
#pragma unroll
      for (int j = 0; j < 4; ++j) {
        int i = q * 4 + j;
        float v2 = vv[i] + (xv[j] - vv[i]) * 0.5f;   // v + (x-v)/tau
        int spk = (v2 - 1.0f >= 0.0f);
        st[(ns + i) * 80 + cl] = spk ? (u16)0x3F80 : (u16)0;
        vv[i] = spk ? 0.0f : v2;
      }
    }
    __syncthreads();
    u16* gp = sT + ((size_t)((t * 8 + b) * 1024 + n0 + nr)) * 512 + c0 + cs;
    *(sh8*)(gp) = *(const sh8*)&st[nr * 80 + cs];
    *(sh8*)(gp + 8) = *(const sh8*)&st[nr * 80 + cs + 8];
    __syncthreads();
  }
}

// ---------------------------------------------------------------------------
// Kernel 3: stacked QKV GEMM (3-split bf16 MFMA) + BN + LIF, spikes out.
// 128x128 tile, BK=32. 2-phase prefetch (double-buffered LDS) + XOR swizzle.
// ---------------------------------------------------------------------------
__global__ __launch_bounds__(256, 2) void qkv_gemm(
    const u16* __restrict__ w3, const u16* __restrict__ sT,
    const float* __restrict__ inv4, const float* __restrict__ add4,
    u16* __restrict__ qs, u16* __restrict__ ks, u16* __restrict__ vs) {
  #pragma clang fp contract(off)
  __shared__ u16 lA[2][3 * 128 * 32];  // [buf][sp][m][k]  2x24.6KB
  __shared__ u16 lB[2][128 * 32];      // [buf][n][k]      2x8KB
  const int tid = threadIdx.x;
  const int m0 = blockIdx.x * 128;
  const int n0 = blockIdx.y * 128;
  const int b = blockIdx.z;
  const int branch = m0 >> 9;
  const int oc0 = m0 & 511;
  u16* dst = branch == 0 ? qs : (branch == 1 ? ks : vs);
  const int lane = tid & 63, wv = tid >> 6;
  const int l15 = lane & 15, l4 = lane >> 4;
  const int wm = wv >> 1, wn = wv & 1;
  const int rA = tid >> 2;
  // swizzle: physical slot p at row r holds logical k-slot p ^ ((r>>1)&3).
  // stage side: lane's dest is (row=tid>>2, p=tid&3) -> fetch logical slot:
  const int kswz = (((tid & 3) ^ ((tid >> 3) & 3)) * 8);
  // read side: logical slot l4 at row (..+l15) lives at physical l4^((l15>>1)&3)
  const int sA = (l4 ^ ((l15 >> 1) & 3)) * 8;

  size_t aoff[6];
#pragma unroll
  for (int c = 0; c < 6; ++c) {
    int rf = c * 64 + rA;
    int sp = rf >> 7, r = rf & 127;
    aoff[c] = (size_t)(sp * 1536 + m0 + r) * 512 + kswz;
  }
  size_t boff[2];
#pragma unroll
  for (int c = 0; c < 2; ++c) boff[c] = (size_t)(c * 64 + rA) * 512 + kswz;

  const f4 fz = {0.f, 0.f, 0.f, 0.f};
  f4 vst[4][4];
#pragma unroll
  for (int i = 0; i < 4; i++)
#pragma unroll
    for (int j = 0; j < 4; j++) vst[i][j] = fz;

  for (int t = 0; t < 4; ++t) {
    f4 acc[4][4];
#pragma unroll
    for (int i = 0; i < 4; i++)
#pragma unroll
      for (int j = 0; j < 4; j++) acc[i][j] = fz;
    const u16* sTt = sT + ((size_t)((t * 8 + b) * 1024 + n0)) * 512;

    auto stage = [&](int buf, int k0) {
#pragma unroll
      for (int c = 0; c < 6; ++c)
        aload16(w3 + aoff[c] + k0, &lA[buf][c * 2048 + tid * 8]);
#pragma unroll
      for (int c = 0; c < 2; ++c)
        aload16(sTt + boff[c] + k0, &lB[buf][c * 2048 + tid * 8]);
    };

    stage(0, 0);
    __syncthreads();
    int cur = 0;
    for (int i = 0; i < 16; ++i) {
      if (i < 15) stage(cur ^ 1, (i + 1) * 32);   // prefetch next K-step
      sh8 bfr[4];
#pragma unroll
      for (int nf = 0; nf < 4; ++nf)
        bfr[nf] = *(const sh8*)&lB[cur][(wn * 64 + nf * 16 + l15) * 32 + sA];
#pragma unroll
      for (int sp = 0; sp < 3; ++sp) {
#pragma unroll
        for (int mf = 0; mf < 4; ++mf) {
          sh8 afr = *(const sh8*)&lA[cur][sp * 4096 + (wm * 64 + mf * 16 + l15) * 32 + sA];
#pragma unroll
          for (int nf = 0; nf < 4; ++nf) acc[mf][nf] = MFMA16(afr, bfr[nf], acc[mf][nf]);
        }
      }
      __syncthreads();   // drains prefetch vmcnt + lgkm; next buf ready
      cur ^= 1;
    }
    // epilogue: BN + LIF + spike store (registers only)
#pragma unroll
    for (int mf = 0; mf < 4; ++mf) {
#pragma unroll
      for (int r = 0; r < 4; ++r) {
        int oc = oc0 + wm * 64 + mf * 16 + l4 * 4 + r;
        float iv = inv4[branch * 512 + oc];
        float ad = add4[branch * 512 + oc];
        size_t rowbase = ((size_t)((t * 8 + b) * 512 + oc)) * 1024 + n0;
#pragma unroll
        for (int nf = 0; nf < 4; ++nf) {
          float z = acc[mf][nf][r] * iv + ad;
          float v2 = vst[mf][nf][r];
          v2 = v2 + (z - v2) * 0.5f;
          int spk = (v2 - 1.0f >= 0.0f);
          vst[mf][nf][r] = spk ? 0.0f : v2;
          dst[rowbase + wn * 64 + nf * 16 + l15] = spk ? (u16)0x3F80 : (u16)0;
        }
      }
    }
  }
}

// ---------------------------------------------------------------------------
// Kernel 4: kvT[e][d] = sum_n v[e,n]*k[d,n], per (t,b,h), split-K in 4 chunks.
// ---------------------------------------------------------------------------
__global__ __launch_bounds__(256) void kv_gemm(const u16* __restrict__ ks,
                                               const u16* __restrict__ vs,
                                               float* __restrict__ kvp) {
  const int tbh = blockIdx.x;  // (t*8+b)*8+h
  const int kc = blockIdx.y;
  const int tid = threadIdx.x;
  const int wv = tid >> 6, lane = tid & 63, l15 = lane & 15, l4 = lane >> 4;
  const size_t cb = ((size_t)(tbh >> 3) * 512 + (size_t)(tbh & 7) * 64) * 1024;
  const u16* vbase = vs + cb;
  const u16* kbase = ks + cb;
  const f4 fz = {0.f, 0.f, 0.f, 0.f};
  f4 acc[4];
#pragma unroll
  for (int i = 0; i < 4; i++) acc[i] = fz;
  for (int s = 0; s < 8; ++s) {
    int kk = kc * 256 + s * 32 + l4 * 8;
    sh8 av = *(const sh8*)(vbase + (size_t)(wv * 16 + l15) * 1024 + kk);
#pragma unroll
    for (int df = 0; df < 4; ++df) {
      sh8 bk = *(const sh8*)(kbase + (size_t)(df * 16 + l15) * 1024 + kk);
      acc[df] = MFMA16(av, bk, acc[df]);
    }
  }
  float* out = kvp + ((size_t)kc * 256 + tbh) * 4096;
#pragma unroll
  for (int df = 0; df < 4; ++df)
#pragma unroll
    for (int r = 0; r < 4; ++r)
      out[(wv * 16 + l4 * 4 + r) * 64 + df * 16 + l15] = acc[df][r];
}

// ---------------------------------------------------------------------------
// Kernel 5: att = (kv^T @ q)*0.125 per head, then LIF; exact integer path.
// ---------------------------------------------------------------------------
__global__ __launch_bounds__(256) void att_lif(const u16* __restrict__ qs,
                                               const float* __restrict__ kvp,
                                               u16* __restrict__ aT) {
  #pragma clang fp contract(off)
  __shared__ u16 ldsb[64 * 72 * 2 + 128 * 72];
  u16* lkhi = ldsb;                 // [64 e][72]
  u16* lklo = ldsb + 64 * 72;       // [64 e][72]
  u16* lqT = ldsb + 64 * 72 * 2;    // [128 n][72]
  u16* lsp = ldsb;                  // alias: [128 n][72] spike transpose buf
  const int tid = threadIdx.x;
  const int n0 = blockIdx.x * 128;
  const int b = blockIdx.y >> 3;
  const int h = blockIdx.y & 7;
  const int wv = tid >> 6, lane = tid & 63, l15 = lane & 15, l4 = lane >> 4;
  const int e_s = tid >> 2, ds_ = (tid & 3) * 16;
  const f4 fz = {0.f, 0.f, 0.f, 0.f};
  f4 vst[4][2];
#pragma unroll
  for (int i = 0; i < 4; i++)
#pragma unroll
    for (int j = 0; j < 2; j++) vst[i][j] = fz;

  for (int t = 0; t < 4; ++t) {
    int tb = t * 8 + b;
    int tbh = tb * 8 + h;
    {  // stage kv: sum 4 partials, split into exact bf16 hi/lo
      const float* base = kvp + (size_t)tbh * 4096 + e_s * 64 + ds_;
#pragma unroll
      for (int q = 0; q < 4; ++q) {
        f4 s4 = fz;
#pragma unroll
        for (int kc = 0; kc < 4; ++kc) s4 += *(const f4*)(base + (size_t)kc * 256 * 4096 + q * 4);
#pragma unroll
        for (int j = 0; j < 4; ++j) {
          float sv = s4[j];
          u16 hb = f2bf(sv);
          float lof = sv - bf2f(hb);
          lkhi[e_s * 72 + ds_ + q * 4 + j] = hb;
          lklo[e_s * 72 + ds_ + q * 4 + j] = f2bf(lof);
        }
      }
    }
    {  // stage q transposed: lqT[n][d]
      const u16* qb = qs + ((size_t)tb * 512 + h * 64) * 1024 + n0;
#pragma unroll
      for (int it = 0; it < 4; ++it) {
        int lin = it * 2048 + tid * 8;
        int d = lin >> 7, j0 = lin & 127;
        sh8 qv = *(const sh8*)(qb + (size_t)d * 1024 + j0);
#pragma unroll
        for (int j = 0; j < 8; ++j) lqT[(j0 + j) * 72 + d] = (u16)qv[j];
      }
    }
    __syncthreads();
    f4 acc[4][2];
#pragma unroll
    for (int i = 0; i < 4; i++)
#pragma unroll
      for (int j = 0; j < 2; j++) acc[i][j] = fz;
#pragma unroll
    for (int ksx = 0; ksx < 2; ++ksx) {
      sh8 bq[2];
#pragma unroll
      for (int nf = 0; nf < 2; ++nf)
        bq[nf] = *(const sh8*)&lqT[(wv * 32 + nf * 16 + l15) * 72 + ksx * 32 + l4 * 8];
#pragma unroll
      for (int mf = 0; mf < 4; ++mf) {
        sh8 ah = *(const sh8*)&lkhi[(mf * 16 + l15) * 72 + ksx * 32 + l4 * 8];
        sh8 al = *(const sh8*)&lklo[(mf * 16 + l15) * 72 + ksx * 32 + l4 * 8];
#pragma unroll
        for (int nf = 0; nf < 2; ++nf) {
          acc[mf][nf] = MFMA16(ah, bq[nf], acc[mf][nf]);
          acc[mf][nf] = MFMA16(al, bq[nf], acc[mf][nf]);
        }
      }
    }
    __syncthreads();  // all reads of lkhi/lklo done before alias overwrite
#pragma unroll
    for (int mf = 0; mf < 4; ++mf)
#pragma unroll
      for (int nf = 0; nf < 2; ++nf)
#pragma unroll
        for (int r = 0; r < 4; ++r) {
          float xatt = acc[mf][nf][r] * 0.125f;  // exact
          float v2 = vst[mf][nf][r];
          v2 = v2 + (xatt - v2) * 0.5f;          // exact dyadic
          int spk = (v2 - 1.0f >= 0.0f);
          vst[mf][nf][r] = spk ? 0.0f : v2;
          int e = mf * 16 + l4 * 4 + r;
          int n = wv * 32 + nf * 16 + l15;
          lsp[n * 72 + e] = spk ? (u16)0x3F80 : (u16)0;
        }
    __syncthreads();
    {  // store a_T rows (c contiguous)
#pragma unroll
      for (int it = 0; it < 2; ++it) {
        int lin = it * 256 + tid;
        int n = lin >> 2, es = (lin & 3) * 16;
        u16* gp = aT + ((size_t)(tb * 1024 + n0 + n)) * 512 + h * 64 + es;
        *(sh8*)gp = *(const sh8*)&lsp[n * 72 + es];
        *(sh8*)(gp + 8) = *(const sh8*)&lsp[n * 72 + es + 8];
      }
    }
    __syncthreads();
  }
}

// ---------------------------------------------------------------------------
// Kernel 6: proj GEMM (3-split) + bias + BN -> out fp32.
// 2-phase prefetch + XOR swizzle (same scheme as qkv_gemm).
// ---------------------------------------------------------------------------
__global__ __launch_bounds__(256, 2) void proj_gemm(
    const u16* __restrict__ w3, const u16* __restrict__ aT,
    const float* __restrict__ inv4, const float* __restrict__ add4,
    const float* __restrict__ pb, float* __restrict__ out) {
  #pragma clang fp contract(off)
  __shared__ u16 lA[2][3 * 128 * 32];
  __shared__ u16 lB[2][128 * 32];
  const int tid = threadIdx.x;
  const int m0 = blockIdx.x * 128;
  const int n0 = blockIdx.y * 128;
  const int tb = blockIdx.z;
  const int lane = tid & 63, wv = tid >> 6;
  const int l15 = lane & 15, l4 = lane >> 4;
  const int wm = wv >> 1, wn = wv & 1;
  const int rA = tid >> 2;
  const int kswz = (((tid & 3) ^ ((tid >> 3) & 3)) * 8);
  const int sA = (l4 ^ ((l15 >> 1) & 3)) * 8;

  size_t aoff[6];
#pragma unroll
  for (int c = 0; c < 6; ++c) {
    int rf = c * 64 + rA;
    int sp = rf >> 7, r = rf & 127;
    aoff[c] = (size_t)(sp * 512 + m0 + r) * 512 + kswz;
  }
  size_t boff[2];
#pragma unroll
  for (int c = 0; c < 2; ++c) boff[c] = (size_t)(c * 64 + rA) * 512 + kswz;

  const f4 fz = {0.f, 0.f, 0.f, 0.f};
  f4 acc[4][4];
#pragma unroll
  for (int i = 0; i < 4; i++)
#pragma unroll
    for (int j = 0; j < 4; j++) acc[i][j] = fz;
  const u16* aTt = aT + ((size_t)tb * 1024 + n0) * 512;

  auto stage = [&](int buf, int k0) {
#pragma unroll
    for (int c = 0; c < 6; ++c)
      aload16(w3 + aoff[c] + k0, &lA[buf][c * 2048 + tid * 8]);
#pragma unroll
    for (int c = 0; c < 2; ++c)
      aload16(aTt + boff[c] + k0, &lB[buf][c * 2048 + tid * 8]);
  };

  stage(0, 0);
  __syncthreads();
  int cur = 0;
  for (int i = 0; i < 16; ++i) {
    if (i < 15) stage(cur ^ 1, (i + 1) * 32);
    sh8 bfr[4];
#pragma unroll
    for (int nf = 0; nf < 4; ++nf)
      bfr[nf] = *(const sh8*)&lB[cur][(wn * 64 + nf * 16 + l15) * 32 + sA];
#pragma unroll
    for (int sp = 0; sp < 3; ++sp) {
#pragma unroll
      for (int mf = 0; mf < 4; ++mf) {
        sh8 afr = *(const sh8*)&lA[cur][sp * 4096 + (wm * 64 + mf * 16 + l15) * 32 + sA];
#pragma unroll
        for (int nf = 0; nf < 4; ++nf) acc[mf][nf] = MFMA16(afr, bfr[nf], acc[mf][nf]);
      }
    }
    __syncthreads();
    cur ^= 1;
  }
#pragma unroll
  for (int mf = 0; mf < 4; ++mf) {
#pragma unroll
    for (int r = 0; r < 4; ++r) {
      int o = m0 + wm * 64 + mf * 16 + l4 * 4 + r;
      float iv = inv4[3 * 512 + o];
      float ad = add4[3 * 512 + o];
      float bias = pb[o];
      size_t rowbase = ((size_t)(tb * 512 + o)) * 1024 + n0;
#pragma unroll
      for (int nf = 0; nf < 4; ++nf) {
        float z = (acc[mf][nf][r] + bias) * iv + ad;
        out[rowbase + wn * 64 + nf * 16 + l15] = z;
      }
    }
  }
}

// ---------------------------------------------------------------------------
extern "C" void kernel_launch(void* const* d_in, const int* in_sizes, int n_in,
                              void* d_out, int out_size, void* d_ws, size_t ws_size,
                              hipStream_t stream) {
  const float* x = (const float*)d_in[0];
  const float* qw = (const float*)d_in[1];
  const float* kw = (const float*)d_in[6];
  const float* vw = (const float*)d_in[11];
  const float* pw = (const float*)d_in[16];
  const float* pb = (const float*)d_in[21];

  char* p = (char*)d_ws;
  u16* w3qkv = (u16*)p; p += (size_t)3 * 1536 * 512 * 2;   // 4.7 MB
  u16* w3p = (u16*)p;   p += (size_t)3 * 512 * 512 * 2;    // 1.6 MB
  float* inv4 = (float*)p; p += 4 * 512 * 4;
  float* add4 = (float*)p; p += 4 * 512 * 4;
  u16* sT = (u16*)p;    p += (size_t)4 * 8 * 1024 * 512 * 2;  // 33.5 MB (reused as aT)
  u16* qs = (u16*)p;    p += (size_t)4 * 8 * 512 * 1024 * 2;
  u16* ks = (u16*)p;    p += (size_t)4 * 8 * 512 * 1024 * 2;
  u16* vs = (u16*)p;    p += (size_t)4 * 8 * 512 * 1024 * 2;
  float* kvp = (float*)p; p += (size_t)4 * 256 * 4096 * 4;    // 16.8 MB
  u16* aT = sT;  // s_T dead after qkv_gemm; reuse region for a_T
  float* out = (float*)d_out;

  prep_weights<<<dim3(2048), dim3(256), 0, stream>>>(qw, kw, vw, pw, w3qkv, w3p);
  for (int s = 0; s < 4; ++s) {
    const float* g  = (const float*)d_in[2 + s * 5];
    const float* be = (const float*)d_in[3 + s * 5];
    const float* mu = (const float*)d_in[4 + s * 5];
    const float* va = (const float*)d_in[5 + s * 5];
    bn_prep<<<dim3(2), dim3(256), 0, stream>>>(g, be, mu, va, inv4 + s * 512, add4 + s * 512);
  }
  lif0<<<dim3(16, 8, 8), dim3(256), 0, stream>>>(x, sT);
  qkv_gemm<<<dim3(12, 8, 8), dim3(256), 0, stream>>>(w3qkv, sT, inv4, add4, qs, ks, vs);
  kv_gemm<<<dim3(256, 4), dim3(256), 0, stream>>>(ks, vs, kvp);
  att_lif<<<dim3(8, 64), dim3(256), 0, stream>>>(qs, kvp, aT);
  proj_gemm<<<dim3(4, 8, 32), dim3(256), 0, stream>>>(w3p, aT, inv4, add4, pb, out);
}

// Round 3
// 264.951 us; speedup vs baseline: 1.3027x; 1.3027x over previous
//
#include <hip/hip_runtime.h>
#include <cstdint>
#include <cstddef>

typedef unsigned short u16;
typedef __attribute__((ext_vector_type(8))) short sh8;       // 8 x 16-bit (4 VGPR)
typedef __attribute__((ext_vector_type(8))) _Float16 hf8;    // 8 fp16 (4 VGPR)
typedef __attribute__((ext_vector_type(4))) float f4;        // 4 f32

#define MFMA16B(a, b, c) __builtin_amdgcn_mfma_f32_16x16x32_bf16((a), (b), (c), 0, 0, 0)
#define MFMA16H(a, b, c) __builtin_amdgcn_mfma_f32_16x16x32_f16((a), (b), (c), 0, 0, 0)

__device__ __forceinline__ u16 f2bf(float f) {
  union { float f; uint32_t u; } v; v.f = f;
  uint32_t u = v.u;
  uint32_t lsb = (u >> 16) & 1u;
  return (u16)((u + 0x7fffu + lsb) >> 16);   // RNE
}
__device__ __forceinline__ float bf2f(u16 h) {
  union { uint32_t u; float f; } v; v.u = ((uint32_t)h) << 16;
  return v.f;
}

// async global->LDS, 16B per lane. LDS dest must be linear in lane order.
__device__ __forceinline__ void aload16(const void* g, void* l) {
  __builtin_amdgcn_global_load_lds(
      (const __attribute__((address_space(1))) uint32_t*)g,
      (__attribute__((address_space(3))) uint32_t*)l, 16, 0, 0);
}

// ---------------------------------------------------------------------------
// Kernel 1: split fp32 weights into 2 fp16 planes (h0 = RNE(w), h1 = RNE(w-h0)).
// ~22-23 effective mantissa bits; residual flush floor ~3e-8 (benign).
// w2qkv layout: [sp][1536][512]; w2p: [sp][512][512]
// ---------------------------------------------------------------------------
__global__ void prep_weights(const float* __restrict__ qw, const float* __restrict__ kw,
                             const float* __restrict__ vw, const float* __restrict__ pw,
                             u16* __restrict__ w2qkv, u16* __restrict__ w2p) {
  #pragma clang fp contract(off)
  int row = blockIdx.x;  // 0..2047
  const float* src;
  u16* dst;
  int M, m;
  if (row < 1536) {
    int br = row >> 9;
    src = (br == 0 ? qw : (br == 1 ? kw : vw)) + (size_t)(row & 511) * 512;
    dst = w2qkv; M = 1536; m = row;
  } else {
    src = pw + (size_t)(row - 1536) * 512;
    dst = w2p; M = 512; m = row - 1536;
  }
  for (int c = threadIdx.x; c < 512; c += 256) {
    float w = src[c];
    _Float16 h0 = (_Float16)w;            // RNE
    float r1 = w - (float)h0;             // exact
    _Float16 h1 = (_Float16)r1;           // RNE
    union { _Float16 h; u16 u; } u0, u1;
    u0.h = h0; u1.h = h1;
    dst[(size_t)m * 512 + c] = u0.u;
    dst[(size_t)(M + m) * 512 + c] = u1.u;
  }
}

__global__ void bn_prep(const float* __restrict__ g, const float* __restrict__ be,
                        const float* __restrict__ mu, const float* __restrict__ va,
                        float* __restrict__ inv, float* __restrict__ add) {
  #pragma clang fp contract(off)
  int i = blockIdx.x * 256 + threadIdx.x;
  if (i < 512) {
    float iv = g[i] / sqrtf(va[i] + 1e-5f);
    inv[i] = iv;
    add[i] = be[i] - mu[i] * iv;
  }
}

// ---------------------------------------------------------------------------
// Kernel 2: LIF over x -> spikes, stored TRANSPOSED sT[t][b][n][c] (fp16: 0x3C00).
// ---------------------------------------------------------------------------
__global__ __launch_bounds__(256) void lif0(const float* __restrict__ x, u16* __restrict__ sT) {
  #pragma clang fp contract(off)
  __shared__ u16 st[64 * 80];   // [n][c] padded
  const int tid = threadIdx.x;
  const int n0 = blockIdx.x * 64;
  const int c0 = blockIdx.y * 64;
  const int b = blockIdx.z;
  const int cl = tid >> 2;
  const int ns = (tid & 3) * 16;
  const int nr = tid >> 2;
  const int cs = (tid & 3) * 16;
  float vv[16];
#pragma unroll
  for (int i = 0; i < 16; i++) vv[i] = 0.f;
  for (int t = 0; t < 4; ++t) {
    const float* xp = x + ((size_t)((t * 8 + b) * 512 + c0 + cl)) * 1024 + n0 + ns;
#pragma unroll
    for (int q = 0; q < 4; ++q) {
      f4 xv = *(const f4*)(xp + q * 4);
#pragma unroll
      for (int j = 0; j < 4; ++j) {
        int i = q * 4 + j;
        float v2 = vv[i] + (xv[j] - vv[i]) * 0.5f;   // v + (x-v)/tau
        int spk = (v2 - 1.0f >= 0.0f);
        st[(ns + i) * 80 + cl] = spk ? (u16)0x3C00 : (u16)0;   // fp16 one
        vv[i] = spk ? 0.0f : v2;
      }
    }
    __syncthreads();
    u16* gp = sT + ((size_t)((t * 8 + b) * 1024 + n0 + nr)) * 512 + c0 + cs;
    *(sh8*)(gp) = *(const sh8*)&st[nr * 80 + cs];
    *(sh8*)(gp + 8) = *(const sh8*)&st[nr * 80 + cs + 8];
    __syncthreads();
  }
}

// ---------------------------------------------------------------------------
// Kernel 3: stacked QKV GEMM (2-plane fp16 MFMA) + BN + LIF, spikes out (bf16).
// 128x128 tile, BK=32, single-buffered LDS (round-1 structure) + XOR swizzle.
// ---------------------------------------------------------------------------
__global__ __launch_bounds__(256, 2) void qkv_gemm(
    const u16* __restrict__ w2, const u16* __restrict__ sT,
    const float* __restrict__ inv4, const float* __restrict__ add4,
    u16* __restrict__ qs, u16* __restrict__ ks, u16* __restrict__ vs) {
  #pragma clang fp contract(off)
  __shared__ u16 lA[2 * 128 * 32];  // [sp][m][k]  16KB
  __shared__ u16 lB[128 * 32];      // [n][k]      8KB
  const int tid = threadIdx.x;
  const int m0 = blockIdx.x * 128;
  const int n0 = blockIdx.y * 128;
  const int b = blockIdx.z;
  const int branch = m0 >> 9;
  const int oc0 = m0 & 511;
  u16* dst = branch == 0 ? qs : (branch == 1 ? ks : vs);
  const int lane = tid & 63, wv = tid >> 6;
  const int l15 = lane & 15, l4 = lane >> 4;
  const int wm = wv >> 1, wn = wv & 1;
  const int rA = tid >> 2;
  // XOR swizzle (verified: conflicts -> 0). physical 16B slot p at row r holds
  // logical slot p ^ ((r>>1)&3). Stage: lane dest (row=tid>>2, p=tid&3).
  const int kswz = (((tid & 3) ^ ((tid >> 3) & 3)) * 8);
  const int sA = (l4 ^ ((l15 >> 1) & 3)) * 8;

  size_t aoff[4];
#pragma unroll
  for (int c = 0; c < 4; ++c) {
    int rf = c * 64 + rA;
    int sp = rf >> 7, r = rf & 127;
    aoff[c] = (size_t)(sp * 1536 + m0 + r) * 512 + kswz;
  }
  size_t boff[2];
#pragma unroll
  for (int c = 0; c < 2; ++c) boff[c] = (size_t)(c * 64 + rA) * 512 + kswz;

  const f4 fz = {0.f, 0.f, 0.f, 0.f};
  f4 vst[4][4];
#pragma unroll
  for (int i = 0; i < 4; i++)
#pragma unroll
    for (int j = 0; j < 4; j++) vst[i][j] = fz;

  for (int t = 0; t < 4; ++t) {
    f4 acc[4][4];
#pragma unroll
    for (int i = 0; i < 4; i++)
#pragma unroll
      for (int j = 0; j < 4; j++) acc[i][j] = fz;
    const u16* sTt = sT + ((size_t)((t * 8 + b) * 1024 + n0)) * 512;

    for (int k0 = 0; k0 < 512; k0 += 32) {
#pragma unroll
      for (int c = 0; c < 4; ++c)   // A: 2 planes x 128 x 32
        aload16(w2 + aoff[c] + k0, &lA[c * 2048 + tid * 8]);
#pragma unroll
      for (int c = 0; c < 2; ++c)   // B: 128 x 32
        aload16(sTt + boff[c] + k0, &lB[c * 2048 + tid * 8]);
      __syncthreads();
      hf8 bfr[4];
#pragma unroll
      for (int nf = 0; nf < 4; ++nf)
        bfr[nf] = *(const hf8*)&lB[(wn * 64 + nf * 16 + l15) * 32 + sA];
#pragma unroll
      for (int sp = 0; sp < 2; ++sp) {
#pragma unroll
        for (int mf = 0; mf < 4; ++mf) {
          hf8 afr = *(const hf8*)&lA[sp * 4096 + (wm * 64 + mf * 16 + l15) * 32 + sA];
#pragma unroll
          for (int nf = 0; nf < 4; ++nf) acc[mf][nf] = MFMA16H(afr, bfr[nf], acc[mf][nf]);
        }
      }
      __syncthreads();
    }
    // epilogue: BN + LIF + spike store (bf16 spikes for kv/att consumers)
#pragma unroll
    for (int mf = 0; mf < 4; ++mf) {
#pragma unroll
      for (int r = 0; r < 4; ++r) {
        int oc = oc0 + wm * 64 + mf * 16 + l4 * 4 + r;
        float iv = inv4[branch * 512 + oc];
        float ad = add4[branch * 512 + oc];
        size_t rowbase = ((size_t)((t * 8 + b) * 512 + oc)) * 1024 + n0;
#pragma unroll
        for (int nf = 0; nf < 4; ++nf) {
          float z = acc[mf][nf][r] * iv + ad;
          float v2 = vst[mf][nf][r];
          v2 = v2 + (z - v2) * 0.5f;
          int spk = (v2 - 1.0f >= 0.0f);
          vst[mf][nf][r] = spk ? 0.0f : v2;
          dst[rowbase + wn * 64 + nf * 16 + l15] = spk ? (u16)0x3F80 : (u16)0;
        }
      }
    }
  }
}

// ---------------------------------------------------------------------------
// Kernel 4: kvT[e][d] = sum_n v[e,n]*k[d,n], per (t,b,h), split-K x4 (bf16, exact).
// ---------------------------------------------------------------------------
__global__ __launch_bounds__(256) void kv_gemm(const u16* __restrict__ ks,
                                               const u16* __restrict__ vs,
                                               float* __restrict__ kvp) {
  const int tbh = blockIdx.x;  // (t*8+b)*8+h
  const int kc = blockIdx.y;
  const int tid = threadIdx.x;
  const int wv = tid >> 6, lane = tid & 63, l15 = lane & 15, l4 = lane >> 4;
  const size_t cb = ((size_t)(tbh >> 3) * 512 + (size_t)(tbh & 7) * 64) * 1024;
  const u16* vbase = vs + cb;
  const u16* kbase = ks + cb;
  const f4 fz = {0.f, 0.f, 0.f, 0.f};
  f4 acc[4];
#pragma unroll
  for (int i = 0; i < 4; i++) acc[i] = fz;
  for (int s = 0; s < 8; ++s) {
    int kk = kc * 256 + s * 32 + l4 * 8;
    sh8 av = *(const sh8*)(vbase + (size_t)(wv * 16 + l15) * 1024 + kk);
#pragma unroll
    for (int df = 0; df < 4; ++df) {
      sh8 bk = *(const sh8*)(kbase + (size_t)(df * 16 + l15) * 1024 + kk);
      acc[df] = MFMA16B(av, bk, acc[df]);
    }
  }
  float* out = kvp + ((size_t)kc * 256 + tbh) * 4096;
#pragma unroll
  for (int df = 0; df < 4; ++df)
#pragma unroll
    for (int r = 0; r < 4; ++r)
      out[(wv * 16 + l4 * 4 + r) * 64 + df * 16 + l15] = acc[df][r];
}

// ---------------------------------------------------------------------------
// Kernel 5: att = (kv^T @ q)*0.125 per head, then LIF; exact integer path.
// Writes aT spikes as fp16 (0x3C00) for the fp16 proj GEMM.
// ---------------------------------------------------------------------------
__global__ __launch_bounds__(256) void att_lif(const u16* __restrict__ qs,
                                               const float* __restrict__ kvp,
                                               u16* __restrict__ aT) {
  #pragma clang fp contract(off)
  __shared__ u16 ldsb[64 * 72 * 2 + 128 * 72];
  u16* lkhi = ldsb;                 // [64 e][72]
  u16* lklo = ldsb + 64 * 72;       // [64 e][72]
  u16* lqT = ldsb + 64 * 72 * 2;    // [128 n][72]
  u16* lsp = ldsb;                  // alias: [128 n][72] spike transpose buf
  const int tid = threadIdx.x;
  const int n0 = blockIdx.x * 128;
  const int b = blockIdx.y >> 3;
  const int h = blockIdx.y & 7;
  const int wv = tid >> 6, lane = tid & 63, l15 = lane & 15, l4 = lane >> 4;
  const int e_s = tid >> 2, ds_ = (tid & 3) * 16;
  const f4 fz = {0.f, 0.f, 0.f, 0.f};
  f4 vst[4][2];
#pragma unroll
  for (int i = 0; i < 4; i++)
#pragma unroll
    for (int j = 0; j < 2; j++) vst[i][j] = fz;

  for (int t = 0; t < 4; ++t) {
    int tb = t * 8 + b;
    int tbh = tb * 8 + h;
    {  // stage kv: sum 4 partials, split into exact bf16 hi/lo
      const float* base = kvp + (size_t)tbh * 4096 + e_s * 64 + ds_;
#pragma unroll
      for (int q = 0; q < 4; ++q) {
        f4 s4 = fz;
#pragma unroll
        for (int kc = 0; kc < 4; ++kc) s4 += *(const f4*)(base + (size_t)kc * 256 * 4096 + q * 4);
#pragma unroll
        for (int j = 0; j < 4; ++j) {
          float sv = s4[j];
          u16 hb = f2bf(sv);
          float lof = sv - bf2f(hb);
          lkhi[e_s * 72 + ds_ + q * 4 + j] = hb;
          lklo[e_s * 72 + ds_ + q * 4 + j] = f2bf(lof);
        }
      }
    }
    {  // stage q transposed: lqT[n][d]
      const u16* qb = qs + ((size_t)tb * 512 + h * 64) * 1024 + n0;
#pragma unroll
      for (int it = 0; it < 4; ++it) {
        int lin = it * 2048 + tid * 8;
        int d = lin >> 7, j0 = lin & 127;
        sh8 qv = *(const sh8*)(qb + (size_t)d * 1024 + j0);
#pragma unroll
        for (int j = 0; j < 8; ++j) lqT[(j0 + j) * 72 + d] = (u16)qv[j];
      }
    }
    __syncthreads();
    f4 acc[4][2];
#pragma unroll
    for (int i = 0; i < 4; i++)
#pragma unroll
      for (int j = 0; j < 2; j++) acc[i][j] = fz;
#pragma unroll
    for (int ksx = 0; ksx < 2; ++ksx) {
      sh8 bq[2];
#pragma unroll
      for (int nf = 0; nf < 2; ++nf)
        bq[nf] = *(const sh8*)&lqT[(wv * 32 + nf * 16 + l15) * 72 + ksx * 32 + l4 * 8];
#pragma unroll
      for (int mf = 0; mf < 4; ++mf) {
        sh8 ah = *(const sh8*)&lkhi[(mf * 16 + l15) * 72 + ksx * 32 + l4 * 8];
        sh8 al = *(const sh8*)&lklo[(mf * 16 + l15) * 72 + ksx * 32 + l4 * 8];
#pragma unroll
        for (int nf = 0; nf < 2; ++nf) {
          acc[mf][nf] = MFMA16B(ah, bq[nf], acc[mf][nf]);
          acc[mf][nf] = MFMA16B(al, bq[nf], acc[mf][nf]);
        }
      }
    }
    __syncthreads();  // all reads of lkhi/lklo done before alias overwrite
#pragma unroll
    for (int mf = 0; mf < 4; ++mf)
#pragma unroll
      for (int nf = 0; nf < 2; ++nf)
#pragma unroll
        for (int r = 0; r < 4; ++r) {
          float xatt = acc[mf][nf][r] * 0.125f;  // exact
          float v2 = vst[mf][nf][r];
          v2 = v2 + (xatt - v2) * 0.5f;          // exact dyadic
          int spk = (v2 - 1.0f >= 0.0f);
          vst[mf][nf][r] = spk ? 0.0f : v2;
          int e = mf * 16 + l4 * 4 + r;
          int n = wv * 32 + nf * 16 + l15;
          lsp[n * 72 + e] = spk ? (u16)0x3C00 : (u16)0;   // fp16 one
        }
    __syncthreads();
    {  // store a_T rows (c contiguous)
#pragma unroll
      for (int it = 0; it < 2; ++it) {
        int lin = it * 256 + tid;
        int n = lin >> 2, es = (lin & 3) * 16;
        u16* gp = aT + ((size_t)(tb * 1024 + n0 + n)) * 512 + h * 64 + es;
        *(sh8*)gp = *(const sh8*)&lsp[n * 72 + es];
        *(sh8*)(gp + 8) = *(const sh8*)&lsp[n * 72 + es + 8];
      }
    }
    __syncthreads();
  }
}

// ---------------------------------------------------------------------------
// Kernel 6: proj GEMM (2-plane fp16) + bias + BN -> out fp32.
// Single-buffer + XOR swizzle (round-1 structure).
// ---------------------------------------------------------------------------
__global__ __launch_bounds__(256, 2) void proj_gemm(
    const u16* __restrict__ w2, const u16* __restrict__ aT,
    const float* __restrict__ inv4, const float* __restrict__ add4,
    const float* __restrict__ pb, float* __restrict__ out) {
  #pragma clang fp contract(off)
  __shared__ u16 lA[2 * 128 * 32];
  __shared__ u16 lB[128 * 32];
  const int tid = threadIdx.x;
  const int m0 = blockIdx.x * 128;
  const int n0 = blockIdx.y * 128;
  const int tb = blockIdx.z;
  const int lane = tid & 63, wv = tid >> 6;
  const int l15 = lane & 15, l4 = lane >> 4;
  const int wm = wv >> 1, wn = wv & 1;
  const int rA = tid >> 2;
  const int kswz = (((tid & 3) ^ ((tid >> 3) & 3)) * 8);
  const int sA = (l4 ^ ((l15 >> 1) & 3)) * 8;

  size_t aoff[4];
#pragma unroll
  for (int c = 0; c < 4; ++c) {
    int rf = c * 64 + rA;
    int sp = rf >> 7, r = rf & 127;
    aoff[c] = (size_t)(sp * 512 + m0 + r) * 512 + kswz;
  }
  size_t boff[2];
#pragma unroll
  for (int c = 0; c < 2; ++c) boff[c] = (size_t)(c * 64 + rA) * 512 + kswz;

  const f4 fz = {0.f, 0.f, 0.f, 0.f};
  f4 acc[4][4];
#pragma unroll
  for (int i = 0; i < 4; i++)
#pragma unroll
    for (int j = 0; j < 4; j++) acc[i][j] = fz;
  const u16* aTt = aT + ((size_t)tb * 1024 + n0) * 512;

  for (int k0 = 0; k0 < 512; k0 += 32) {
#pragma unroll
    for (int c = 0; c < 4; ++c)
      aload16(w2 + aoff[c] + k0, &lA[c * 2048 + tid * 8]);
#pragma unroll
    for (int c = 0; c < 2; ++c)
      aload16(aTt + boff[c] + k0, &lB[c * 2048 + tid * 8]);
    __syncthreads();
    hf8 bfr[4];
#pragma unroll
    for (int nf = 0; nf < 4; ++nf)
      bfr[nf] = *(const hf8*)&lB[(wn * 64 + nf * 16 + l15) * 32 + sA];
#pragma unroll
    for (int sp = 0; sp < 2; ++sp) {
#pragma unroll
      for (int mf = 0; mf < 4; ++mf) {
        hf8 afr = *(const hf8*)&lA[sp * 4096 + (wm * 64 + mf * 16 + l15) * 32 + sA];
#pragma unroll
        for (int nf = 0; nf < 4; ++nf) acc[mf][nf] = MFMA16H(afr, bfr[nf], acc[mf][nf]);
      }
    }
    __syncthreads();
  }
#pragma unroll
  for (int mf = 0; mf < 4; ++mf) {
#pragma unroll
    for (int r = 0; r < 4; ++r) {
      int o = m0 + wm * 64 + mf * 16 + l4 * 4 + r;
      float iv = inv4[3 * 512 + o];
      float ad = add4[3 * 512 + o];
      float bias = pb[o];
      size_t rowbase = ((size_t)(tb * 512 + o)) * 1024 + n0;
#pragma unroll
      for (int nf = 0; nf < 4; ++nf) {
        float z = (acc[mf][nf][r] + bias) * iv + ad;
        out[rowbase + wn * 64 + nf * 16 + l15] = z;
      }
    }
  }
}

// ---------------------------------------------------------------------------
extern "C" void kernel_launch(void* const* d_in, const int* in_sizes, int n_in,
                              void* d_out, int out_size, void* d_ws, size_t ws_size,
                              hipStream_t stream) {
  const float* x = (const float*)d_in[0];
  const float* qw = (const float*)d_in[1];
  const float* kw = (const float*)d_in[6];
  const float* vw = (const float*)d_in[11];
  const float* pw = (const float*)d_in[16];
  const float* pb = (const float*)d_in[21];

  char* p = (char*)d_ws;
  u16* w2qkv = (u16*)p; p += (size_t)2 * 1536 * 512 * 2;   // 3.1 MB
  u16* w2p = (u16*)p;   p += (size_t)2 * 512 * 512 * 2;    // 1.0 MB
  float* inv4 = (float*)p; p += 4 * 512 * 4;
  float* add4 = (float*)p; p += 4 * 512 * 4;
  u16* sT = (u16*)p;    p += (size_t)4 * 8 * 1024 * 512 * 2;  // 33.5 MB (reused as aT)
  u16* qs = (u16*)p;    p += (size_t)4 * 8 * 512 * 1024 * 2;
  u16* ks = (u16*)p;    p += (size_t)4 * 8 * 512 * 1024 * 2;
  u16* vs = (u16*)p;    p += (size_t)4 * 8 * 512 * 1024 * 2;
  float* kvp = (float*)p; p += (size_t)4 * 256 * 4096 * 4;    // 16.8 MB
  u16* aT = sT;  // s_T dead after qkv_gemm; reuse region for a_T
  float* out = (float*)d_out;

  prep_weights<<<dim3(2048), dim3(256), 0, stream>>>(qw, kw, vw, pw, w2qkv, w2p);
  for (int s = 0; s < 4; ++s) {
    const float* g  = (const float*)d_in[2 + s * 5];
    const float* be = (const float*)d_in[3 + s * 5];
    const float* mu = (const float*)d_in[4 + s * 5];
    const float* va = (const float*)d_in[5 + s * 5];
    bn_prep<<<dim3(2), dim3(256), 0, stream>>>(g, be, mu, va, inv4 + s * 512, add4 + s * 512);
  }
  lif0<<<dim3(16, 8, 8), dim3(256), 0, stream>>>(x, sT);
  qkv_gemm<<<dim3(12, 8, 8), dim3(256), 0, stream>>>(w2qkv, sT, inv4, add4, qs, ks, vs);
  kv_gemm<<<dim3(256, 4), dim3(256), 0, stream>>>(ks, vs, kvp);
  att_lif<<<dim3(8, 64), dim3(256), 0, stream>>>(qs, kvp, aT);
  proj_gemm<<<dim3(4, 8, 32), dim3(256), 0, stream>>>(w2p, aT, inv4, add4, pb, out);
}

// Round 4
// 251.608 us; speedup vs baseline: 1.3717x; 1.0530x over previous
//
#include <hip/hip_runtime.h>
#include <cstdint>
#include <cstddef>

typedef unsigned short u16;
typedef __attribute__((ext_vector_type(8))) short sh8;       // 8 x 16-bit (4 VGPR)
typedef __attribute__((ext_vector_type(8))) _Float16 hf8;    // 8 fp16 (4 VGPR)
typedef __attribute__((ext_vector_type(4))) float f4;        // 4 f32

#define MFMA16B(a, b, c) __builtin_amdgcn_mfma_f32_16x16x32_bf16((a), (b), (c), 0, 0, 0)
#define MFMA16H(a, b, c) __builtin_amdgcn_mfma_f32_16x16x32_f16((a), (b), (c), 0, 0, 0)

__device__ __forceinline__ u16 f2bf(float f) {
  union { float f; uint32_t u; } v; v.f = f;
  uint32_t u = v.u;
  uint32_t lsb = (u >> 16) & 1u;
  return (u16)((u + 0x7fffu + lsb) >> 16);   // RNE
}
__device__ __forceinline__ float bf2f(u16 h) {
  union { uint32_t u; float f; } v; v.u = ((uint32_t)h) << 16;
  return v.f;
}

// async global->LDS, 16B per lane. LDS dest must be linear in lane order.
__device__ __forceinline__ void aload16(const void* g, void* l) {
  __builtin_amdgcn_global_load_lds(
      (const __attribute__((address_space(1))) uint32_t*)g,
      (__attribute__((address_space(3))) uint32_t*)l, 16, 0, 0);
}

__device__ __forceinline__ void pbar() {            // phase barrier (no drain)
  __builtin_amdgcn_sched_barrier(0);
  __builtin_amdgcn_s_barrier();
  __builtin_amdgcn_sched_barrier(0);
}
__device__ __forceinline__ void tile_bar() {        // tile boundary: drain own vm, sync
  asm volatile("s_waitcnt vmcnt(0)" ::: "memory");
  __builtin_amdgcn_s_barrier();
  __builtin_amdgcn_sched_barrier(0);
}

// 12 MFMAs for one quadrant; MH/NH must be literal constants.
#define QUAD12(Af, Bf, MH, NH)                                                \
  {                                                                           \
    __builtin_amdgcn_s_setprio(1);                                            \
    _Pragma("unroll") for (int kk = 0; kk < 2; ++kk)                          \
      _Pragma("unroll") for (int nf = 0; nf < 2; ++nf)                        \
        _Pragma("unroll") for (int mf = 0; mf < 3; ++mf)                      \
          acc[(MH)*3 + mf][(NH)*2 + nf] = MFMA16H(                            \
              Af[mf][kk], Bf[nf][kk], acc[(MH)*3 + mf][(NH)*2 + nf]);         \
    __builtin_amdgcn_s_setprio(0);                                            \
  }

// ---------------------------------------------------------------------------
// Kernel 1: split fp32 weights into 2 fp16 planes.
// qkv layout: [1536][1024] rows = (q|k|v), cols 0-511 = h0, 512-1023 = h1.
// proj layout: [sp][512][512] (old style, for the unchanged proj kernel).
// ---------------------------------------------------------------------------
__global__ void prep_weights(const float* __restrict__ qw, const float* __restrict__ kw,
                             const float* __restrict__ vw, const float* __restrict__ pw,
                             u16* __restrict__ w2qkv, u16* __restrict__ w2p) {
  #pragma clang fp contract(off)
  int row = blockIdx.x;  // 0..2047
  for (int c = threadIdx.x; c < 512; c += 256) {
    const float* src;
    if (row < 1536) {
      int br = row >> 9;
      src = (br == 0 ? qw : (br == 1 ? kw : vw)) + (size_t)(row & 511) * 512;
    } else {
      src = pw + (size_t)(row - 1536) * 512;
    }
    float w = src[c];
    _Float16 h0 = (_Float16)w;
    float r1 = w - (float)h0;
    _Float16 h1 = (_Float16)r1;
    union { _Float16 h; u16 u; } u0, u1;
    u0.h = h0; u1.h = h1;
    if (row < 1536) {
      w2qkv[(size_t)row * 1024 + c] = u0.u;
      w2qkv[(size_t)row * 1024 + 512 + c] = u1.u;
    } else {
      int m = row - 1536;
      w2p[(size_t)m * 512 + c] = u0.u;
      w2p[(size_t)(512 + m) * 512 + c] = u1.u;
    }
  }
}

__global__ void bn_prep(const float* __restrict__ g, const float* __restrict__ be,
                        const float* __restrict__ mu, const float* __restrict__ va,
                        float* __restrict__ inv, float* __restrict__ add) {
  #pragma clang fp contract(off)
  int i = blockIdx.x * 256 + threadIdx.x;
  if (i < 512) {
    float iv = g[i] / sqrtf(va[i] + 1e-5f);
    inv[i] = iv;
    add[i] = be[i] - mu[i] * iv;
  }
}

// ---------------------------------------------------------------------------
// Kernel 2: LIF over x -> spikes, stored TRANSPOSED sT[t][b][n][c] (fp16: 0x3C00).
// ---------------------------------------------------------------------------
__global__ __launch_bounds__(256) void lif0(const float* __restrict__ x, u16* __restrict__ sT) {
  #pragma clang fp contract(off)
  __shared__ u16 st[64 * 80];   // [n][c] padded
  const int tid = threadIdx.x;
  const int n0 = blockIdx.x * 64;
  const int c0 = blockIdx.y * 64;
  const int b = blockIdx.z;
  const int cl = tid >> 2;
  const int ns = (tid & 3) * 16;
  const int nr = tid >> 2;
  const int cs = (tid & 3) * 16;
  float vv[16];
#pragma unroll
  for (int i = 0; i < 16; i++) vv[i] = 0.f;
  for (int t = 0; t < 4; ++t) {
    const float* xp = x + ((size_t)((t * 8 + b) * 512 + c0 + cl)) * 1024 + n0 + ns;
#pragma unroll
    for (int q = 0; q < 4; ++q) {
      f4 xv = *(const f4*)(xp + q * 4);
#pragma unroll
      for (int j = 0; j < 4; ++j) {
        int i = q * 4 + j;
        float v2 = vv[i] + (xv[j] - vv[i]) * 0.5f;   // v + (x-v)/tau
        int spk = (v2 - 1.0f >= 0.0f);
        st[(ns + i) * 80 + cl] = spk ? (u16)0x3C00 : (u16)0;   // fp16 one
        vv[i] = spk ? 0.0f : v2;
      }
    }
    __syncthreads();
    u16* gp = sT + ((size_t)((t * 8 + b) * 1024 + n0 + nr)) * 512 + c0 + cs;
    *(sh8*)(gp) = *(const sh8*)&st[nr * 80 + cs];
    *(sh8*)(gp + 8) = *(const sh8*)&st[nr * 80 + cs + 8];
    __syncthreads();
  }
}

// ---------------------------------------------------------------------------
// Kernel 3: stacked QKV GEMM (fp16 planes folded into K'=1024) + BN + LIF.
// BM=192 BN=256 BK=64, 512 threads (2Mx4N waves, 96x64/wave), dbuf LDS,
// 4 quadrant-phases + raw barriers + tile-boundary vmcnt(0). Grid 256 = 1/CU.
// ---------------------------------------------------------------------------
__global__ __launch_bounds__(512, 2) void qkv_gemm(
    const u16* __restrict__ w2,      // [1536][1024]
    const u16* __restrict__ sT,      // [t][b][n][512]
    const float* __restrict__ inv4, const float* __restrict__ add4,
    u16* __restrict__ qs, u16* __restrict__ ks, u16* __restrict__ vs) {
  #pragma clang fp contract(off)
  __shared__ u16 lA[2][192 * 64];   // 2 x 24KB
  __shared__ u16 lB[2][256 * 64];   // 2 x 32KB
  const int tid = threadIdx.x;
  const int bid = blockIdx.x;               // 256 blocks
  const int orig = (bid & 7) * 32 + (bid >> 3);   // XCD-chunked (256%8==0)
  const int mI = orig & 7;
  const int nI = (orig >> 3) & 3;
  const int b  = orig >> 5;
  const int m0 = mI * 192;
  const int n0 = nI * 256;
  const int wid = tid >> 6, lane = tid & 63;
  const int l15 = lane & 15, l4 = lane >> 4;
  const int wm = wid >> 2, wn = wid & 3;    // 2M x 4N
  // staging: thread -> (row = tid>>3 within 64-row chunk, phys slot = tid&7);
  // logical k-slot to fetch = phys ^ (row&7)  [both-sides swizzle]
  const int srow = tid >> 3;
  const int sslot = (tid & 7) ^ (srow & 7);
  int aoff[3];
#pragma unroll
  for (int c = 0; c < 3; ++c)
    aoff[c] = (m0 + c * 64 + srow) * 1024 + sslot * 8;
  int boff[4];
#pragma unroll
  for (int c = 0; c < 4; ++c)
    boff[c] = (n0 + c * 64 + srow) * 512 + sslot * 8;

  auto stA = [&](int bf, int ii) {
    int k0 = (ii & 15) * 64;
#pragma unroll
    for (int c = 0; c < 3; ++c)
      aload16(w2 + (size_t)aoff[c] + k0, &lA[bf][c * 4096 + tid * 8]);
  };
  auto stB = [&](int bf, int ii, int c0) {
    int bk0 = (ii & 7) * 64;                 // k0 mod 512 (B rows duplicated)
    int tt = ii >> 4;
    const u16* bb = sT + (size_t)tt * 4194304 + (size_t)b * 524288;
#pragma unroll
    for (int c = c0; c < c0 + 2; ++c)
      aload16(bb + (size_t)boff[c] + bk0, &lB[bf][c * 4096 + tid * 8]);
  };

  const f4 fz = {0.f, 0.f, 0.f, 0.f};
  f4 acc[6][4];
  f4 vst[6][4];
#pragma unroll
  for (int i = 0; i < 6; i++)
#pragma unroll
    for (int j = 0; j < 4; j++) vst[i][j] = fz;

  // prime tile 0
  stA(0, 0); stB(0, 0, 0); stB(0, 0, 2);
  tile_bar();
  int buf = 0;

  for (int t = 0; t < 4; ++t) {
#pragma unroll
    for (int i = 0; i < 6; i++)
#pragma unroll
      for (int j = 0; j < 4; j++) acc[i][j] = fz;

    for (int i = 0; i < 16; ++i) {
      const int ii = t * 16 + i;
      const bool pf = (ii < 63);
      // ---- phase 0: read A(mh0)+B(nh0); prefetch A(next)
      hf8 A0[3][2], Bq[2][2];
#pragma unroll
      for (int mf = 0; mf < 3; ++mf)
#pragma unroll
        for (int kk = 0; kk < 2; ++kk) {
          int lr = wm * 96 + mf * 16 + l15;
          A0[mf][kk] = *(const hf8*)&lA[buf][lr * 64 + (((kk * 4 + l4) ^ (l15 & 7)) * 8)];
        }
#pragma unroll
      for (int nf = 0; nf < 2; ++nf)
#pragma unroll
        for (int kk = 0; kk < 2; ++kk) {
          int lr = wn * 64 + nf * 16 + l15;
          Bq[nf][kk] = *(const hf8*)&lB[buf][lr * 64 + (((kk * 4 + l4) ^ (l15 & 7)) * 8)];
        }
      if (pf) stA(buf ^ 1, ii + 1);
      pbar();
      QUAD12(A0, Bq, 0, 0);
      // ---- phase 1: read B(nh1); prefetch B chunk 0-1
      hf8 B1[2][2];
#pragma unroll
      for (int nf = 0; nf < 2; ++nf)
#pragma unroll
        for (int kk = 0; kk < 2; ++kk) {
          int lr = wn * 64 + (2 + nf) * 16 + l15;
          B1[nf][kk] = *(const hf8*)&lB[buf][lr * 64 + (((kk * 4 + l4) ^ (l15 & 7)) * 8)];
        }
      if (pf) stB(buf ^ 1, ii + 1, 0);
      pbar();
      QUAD12(A0, B1, 0, 1);
      // ---- phase 2: read A(mh1); prefetch B chunk 2-3
      hf8 A1[3][2];
#pragma unroll
      for (int mf = 0; mf < 3; ++mf)
#pragma unroll
        for (int kk = 0; kk < 2; ++kk) {
          int lr = wm * 96 + (3 + mf) * 16 + l15;
          A1[mf][kk] = *(const hf8*)&lA[buf][lr * 64 + (((kk * 4 + l4) ^ (l15 & 7)) * 8)];
        }
      if (pf) stB(buf ^ 1, ii + 1, 2);
      pbar();
      QUAD12(A1, B1, 1, 1);
      // ---- phase 3: re-read B(nh0)
#pragma unroll
      for (int nf = 0; nf < 2; ++nf)
#pragma unroll
        for (int kk = 0; kk < 2; ++kk) {
          int lr = wn * 64 + nf * 16 + l15;
          Bq[nf][kk] = *(const hf8*)&lB[buf][lr * 64 + (((kk * 4 + l4) ^ (l15 & 7)) * 8)];
        }
      pbar();
      QUAD12(A1, Bq, 1, 0);
      tile_bar();        // drain own prefetch vm; all waves done with this buf
      buf ^= 1;
    }
    // epilogue: BN + LIF + spike store (bf16 spikes)
#pragma unroll
    for (int mf = 0; mf < 6; ++mf) {
      int f0 = m0 + wm * 96 + mf * 16;       // 16-aligned; never crosses 512
      int br = f0 >> 9;
      u16* dst = br == 0 ? qs : (br == 1 ? ks : vs);
      int ocb = f0 & 511;
#pragma unroll
      for (int r = 0; r < 4; ++r) {
        int oc = ocb + l4 * 4 + r;
        float iv = inv4[br * 512 + oc];
        float ad = add4[br * 512 + oc];
        size_t rowbase = ((size_t)((t * 8 + b) * 512 + oc)) * 1024 + n0;
#pragma unroll
        for (int nf = 0; nf < 4; ++nf) {
          float z = acc[mf][nf][r] * iv + ad;
          float v2 = vst[mf][nf][r];
          v2 = v2 + (z - v2) * 0.5f;
          int spk = (v2 - 1.0f >= 0.0f);
          vst[mf][nf][r] = spk ? 0.0f : v2;
          dst[rowbase + wn * 64 + nf * 16 + l15] = spk ? (u16)0x3F80 : (u16)0;
        }
      }
    }
  }
}

// ---------------------------------------------------------------------------
// Kernel 4: kvT[e][d] = sum_n v[e,n]*k[d,n], per (t,b,h), single pass K=1024.
// Exact integers (<=1024) in fp32 MFMA chain. kvp[tbh][64][64].
// ---------------------------------------------------------------------------
__global__ __launch_bounds__(256) void kv_gemm(const u16* __restrict__ ks,
                                               const u16* __restrict__ vs,
                                               float* __restrict__ kvp) {
  const int tbh = blockIdx.x;  // (t*8+b)*8+h ; 256 blocks
  const int tid = threadIdx.x;
  const int wv = tid >> 6, lane = tid & 63, l15 = lane & 15, l4 = lane >> 4;
  const size_t cb = ((size_t)(tbh >> 3) * 512 + (size_t)(tbh & 7) * 64) * 1024;
  const u16* vbase = vs + cb;
  const u16* kbase = ks + cb;
  const f4 fz = {0.f, 0.f, 0.f, 0.f};
  f4 acc[4];
#pragma unroll
  for (int i = 0; i < 4; i++) acc[i] = fz;
  for (int s = 0; s < 32; ++s) {
    int kk = s * 32 + l4 * 8;
    sh8 av = *(const sh8*)(vbase + (size_t)(wv * 16 + l15) * 1024 + kk);
#pragma unroll
    for (int df = 0; df < 4; ++df) {
      sh8 bk = *(const sh8*)(kbase + (size_t)(df * 16 + l15) * 1024 + kk);
      acc[df] = MFMA16B(av, bk, acc[df]);
    }
  }
  float* out = kvp + (size_t)tbh * 4096;
#pragma unroll
  for (int df = 0; df < 4; ++df)
#pragma unroll
    for (int r = 0; r < 4; ++r)
      out[(wv * 16 + l4 * 4 + r) * 64 + df * 16 + l15] = acc[df][r];
}

// ---------------------------------------------------------------------------
// Kernel 5: att = (kv^T @ q)*0.125 per head, then LIF; exact integer path.
// ---------------------------------------------------------------------------
__global__ __launch_bounds__(256) void att_lif(const u16* __restrict__ qs,
                                               const float* __restrict__ kvp,
                                               u16* __restrict__ aT) {
  #pragma clang fp contract(off)
  __shared__ u16 ldsb[64 * 72 * 2 + 128 * 72];
  u16* lkhi = ldsb;                 // [64 e][72]
  u16* lklo = ldsb + 64 * 72;       // [64 e][72]
  u16* lqT = ldsb + 64 * 72 * 2;    // [128 n][72]
  u16* lsp = ldsb;                  // alias: [128 n][72] spike transpose buf
  const int tid = threadIdx.x;
  const int n0 = blockIdx.x * 128;
  const int b = blockIdx.y >> 3;
  const int h = blockIdx.y & 7;
  const int wv = tid >> 6, lane = tid & 63, l15 = lane & 15, l4 = lane >> 4;
  const int e_s = tid >> 2, ds_ = (tid & 3) * 16;
  const f4 fz = {0.f, 0.f, 0.f, 0.f};
  f4 vst[4][2];
#pragma unroll
  for (int i = 0; i < 4; i++)
#pragma unroll
    for (int j = 0; j < 2; j++) vst[i][j] = fz;

  for (int t = 0; t < 4; ++t) {
    int tb = t * 8 + b;
    int tbh = tb * 8 + h;
    {  // stage kv: split into exact bf16 hi/lo
      const float* base = kvp + (size_t)tbh * 4096 + e_s * 64 + ds_;
#pragma unroll
      for (int q = 0; q < 4; ++q) {
        f4 s4 = *(const f4*)(base + q * 4);
#pragma unroll
        for (int j = 0; j < 4; ++j) {
          float sv = s4[j];
          u16 hb = f2bf(sv);
          float lof = sv - bf2f(hb);
          lkhi[e_s * 72 + ds_ + q * 4 + j] = hb;
          lklo[e_s * 72 + ds_ + q * 4 + j] = f2bf(lof);
        }
      }
    }
    {  // stage q transposed: lqT[n][d]
      const u16* qb = qs + ((size_t)tb * 512 + h * 64) * 1024 + n0;
#pragma unroll
      for (int it = 0; it < 4; ++it) {
        int lin = it * 2048 + tid * 8;
        int d = lin >> 7, j0 = lin & 127;
        sh8 qv = *(const sh8*)(qb + (size_t)d * 1024 + j0);
#pragma unroll
        for (int j = 0; j < 8; ++j) lqT[(j0 + j) * 72 + d] = (u16)qv[j];
      }
    }
    __syncthreads();
    f4 acc[4][2];
#pragma unroll
    for (int i = 0; i < 4; i++)
#pragma unroll
      for (int j = 0; j < 2; j++) acc[i][j] = fz;
#pragma unroll
    for (int ksx = 0; ksx < 2; ++ksx) {
      sh8 bq[2];
#pragma unroll
      for (int nf = 0; nf < 2; ++nf)
        bq[nf] = *(const sh8*)&lqT[(wv * 32 + nf * 16 + l15) * 72 + ksx * 32 + l4 * 8];
#pragma unroll
      for (int mf = 0; mf < 4; ++mf) {
        sh8 ah = *(const sh8*)&lkhi[(mf * 16 + l15) * 72 + ksx * 32 + l4 * 8];
        sh8 al = *(const sh8*)&lklo[(mf * 16 + l15) * 72 + ksx * 32 + l4 * 8];
#pragma unroll
        for (int nf = 0; nf < 2; ++nf) {
          acc[mf][nf] = MFMA16B(ah, bq[nf], acc[mf][nf]);
          acc[mf][nf] = MFMA16B(al, bq[nf], acc[mf][nf]);
        }
      }
    }
    __syncthreads();  // all reads of lkhi/lklo done before alias overwrite
#pragma unroll
    for (int mf = 0; mf < 4; ++mf)
#pragma unroll
      for (int nf = 0; nf < 2; ++nf)
#pragma unroll
        for (int r = 0; r < 4; ++r) {
          float xatt = acc[mf][nf][r] * 0.125f;  // exact
          float v2 = vst[mf][nf][r];
          v2 = v2 + (xatt - v2) * 0.5f;          // exact dyadic
          int spk = (v2 - 1.0f >= 0.0f);
          vst[mf][nf][r] = spk ? 0.0f : v2;
          int e = mf * 16 + l4 * 4 + r;
          int n = wv * 32 + nf * 16 + l15;
          lsp[n * 72 + e] = spk ? (u16)0x3C00 : (u16)0;   // fp16 one
        }
    __syncthreads();
    {  // store a_T rows (c contiguous)
#pragma unroll
      for (int it = 0; it < 2; ++it) {
        int lin = it * 256 + tid;
        int n = lin >> 2, es = (lin & 3) * 16;
        u16* gp = aT + ((size_t)(tb * 1024 + n0 + n)) * 512 + h * 64 + es;
        *(sh8*)gp = *(const sh8*)&lsp[n * 72 + es];
        *(sh8*)(gp + 8) = *(const sh8*)&lsp[n * 72 + es + 8];
      }
    }
    __syncthreads();
  }
}

// ---------------------------------------------------------------------------
// Kernel 6: proj GEMM (2-plane fp16) + bias + BN -> out fp32 (round-3 structure).
// ---------------------------------------------------------------------------
__global__ __launch_bounds__(256, 2) void proj_gemm(
    const u16* __restrict__ w2, const u16* __restrict__ aT,
    const float* __restrict__ inv4, const float* __restrict__ add4,
    const float* __restrict__ pb, float* __restrict__ out) {
  #pragma clang fp contract(off)
  __shared__ u16 lA[2 * 128 * 32];
  __shared__ u16 lB[128 * 32];
  const int tid = threadIdx.x;
  const int m0 = blockIdx.x * 128;
  const int n0 = blockIdx.y * 128;
  const int tb = blockIdx.z;
  const int lane = tid & 63, wv = tid >> 6;
  const int l15 = lane & 15, l4 = lane >> 4;
  const int wm = wv >> 1, wn = wv & 1;
  const int rA = tid >> 2;
  const int kswz = (((tid & 3) ^ ((tid >> 3) & 3)) * 8);
  const int sA = (l4 ^ ((l15 >> 1) & 3)) * 8;

  size_t aoff[4];
#pragma unroll
  for (int c = 0; c < 4; ++c) {
    int rf = c * 64 + rA;
    int sp = rf >> 7, r = rf & 127;
    aoff[c] = (size_t)(sp * 512 + m0 + r) * 512 + kswz;
  }
  size_t boff[2];
#pragma unroll
  for (int c = 0; c < 2; ++c) boff[c] = (size_t)(c * 64 + rA) * 512 + kswz;

  const f4 fz = {0.f, 0.f, 0.f, 0.f};
  f4 acc[4][4];
#pragma unroll
  for (int i = 0; i < 4; i++)
#pragma unroll
    for (int j = 0; j < 4; j++) acc[i][j] = fz;
  const u16* aTt = aT + ((size_t)tb * 1024 + n0) * 512;

  for (int k0 = 0; k0 < 512; k0 += 32) {
#pragma unroll
    for (int c = 0; c < 4; ++c)
      aload16(w2 + aoff[c] + k0, &lA[c * 2048 + tid * 8]);
#pragma unroll
    for (int c = 0; c < 2; ++c)
      aload16(aTt + boff[c] + k0, &lB[c * 2048 + tid * 8]);
    __syncthreads();
    hf8 bfr[4];
#pragma unroll
    for (int nf = 0; nf < 4; ++nf)
      bfr[nf] = *(const hf8*)&lB[(wn * 64 + nf * 16 + l15) * 32 + sA];
#pragma unroll
    for (int sp = 0; sp < 2; ++sp) {
#pragma unroll
      for (int mf = 0; mf < 4; ++mf) {
        hf8 afr = *(const hf8*)&lA[sp * 4096 + (wm * 64 + mf * 16 + l15) * 32 + sA];
#pragma unroll
        for (int nf = 0; nf < 4; ++nf) acc[mf][nf] = MFMA16H(afr, bfr[nf], acc[mf][nf]);
      }
    }
    __syncthreads();
  }
#pragma unroll
  for (int mf = 0; mf < 4; ++mf) {
#pragma unroll
    for (int r = 0; r < 4; ++r) {
      int o = m0 + wm * 64 + mf * 16 + l4 * 4 + r;
      float iv = inv4[3 * 512 + o];
      float ad = add4[3 * 512 + o];
      float bias = pb[o];
      size_t rowbase = ((size_t)(tb * 512 + o)) * 1024 + n0;
#pragma unroll
      for (int nf = 0; nf < 4; ++nf) {
        float z = (acc[mf][nf][r] + bias) * iv + ad;
        out[rowbase + wn * 64 + nf * 16 + l15] = z;
      }
    }
  }
}

// ---------------------------------------------------------------------------
extern "C" void kernel_launch(void* const* d_in, const int* in_sizes, int n_in,
                              void* d_out, int out_size, void* d_ws, size_t ws_size,
                              hipStream_t stream) {
  const float* x = (const float*)d_in[0];
  const float* qw = (const float*)d_in[1];
  const float* kw = (const float*)d_in[6];
  const float* vw = (const float*)d_in[11];
  const float* pw = (const float*)d_in[16];
  const float* pb = (const float*)d_in[21];

  char* p = (char*)d_ws;
  u16* w2qkv = (u16*)p; p += (size_t)1536 * 1024 * 2;      // 3.1 MB
  u16* w2p = (u16*)p;   p += (size_t)2 * 512 * 512 * 2;    // 1.0 MB
  float* inv4 = (float*)p; p += 4 * 512 * 4;
  float* add4 = (float*)p; p += 4 * 512 * 4;
  u16* sT = (u16*)p;    p += (size_t)4 * 8 * 1024 * 512 * 2;  // 33.5 MB (reused as aT)
  u16* qs = (u16*)p;    p += (size_t)4 * 8 * 512 * 1024 * 2;
  u16* ks = (u16*)p;    p += (size_t)4 * 8 * 512 * 1024 * 2;
  u16* vs = (u16*)p;    p += (size_t)4 * 8 * 512 * 1024 * 2;
  float* kvp = (float*)p; p += (size_t)256 * 4096 * 4;        // 4.2 MB
  u16* aT = sT;  // s_T dead after qkv_gemm; reuse region for a_T
  float* out = (float*)d_out;

  prep_weights<<<dim3(2048), dim3(256), 0, stream>>>(qw, kw, vw, pw, w2qkv, w2p);
  for (int s = 0; s < 4; ++s) {
    const float* g  = (const float*)d_in[2 + s * 5];
    const float* be = (const float*)d_in[3 + s * 5];
    const float* mu = (const float*)d_in[4 + s * 5];
    const float* va = (const float*)d_in[5 + s * 5];
    bn_prep<<<dim3(2), dim3(256), 0, stream>>>(g, be, mu, va, inv4 + s * 512, add4 + s * 512);
  }
  lif0<<<dim3(16, 8, 8), dim3(256), 0, stream>>>(x, sT);
  qkv_gemm<<<dim3(256), dim3(512), 0, stream>>>(w2qkv, sT, inv4, add4, qs, ks, vs);
  kv_gemm<<<dim3(256), dim3(256), 0, stream>>>(ks, vs, kvp);
  att_lif<<<dim3(8, 64), dim3(256), 0, stream>>>(qs, kvp, aT);
  proj_gemm<<<dim3(4, 8, 32), dim3(256), 0, stream>>>(w2p, aT, inv4, add4, pb, out);
}